// Round 21
// baseline (196.752 us; speedup 1.0000x reference)
//
#include <hip/hip_runtime.h>
#include <hip/hip_bf16.h>
#include <math.h>

#define B_ 128
#define L_ 50
#define D_ 128
#define S_ 12
#define NEG_INF_ -9e15f

typedef __attribute__((ext_vector_type(8))) _Float16 half8;
typedef __attribute__((ext_vector_type(4))) float f32x4;

static __device__ __forceinline__ float lrelu(float x){ return fmaxf(x, 0.2f*x); }
static __device__ __forceinline__ float fexp(float x){ return __expf(x); }
static __device__ __forceinline__ float frcp(float x){ return __builtin_amdgcn_rcpf(x); }

// ---------------------------------------------------------------------------
// Local aggregator: 4-edge-type GAT. Grid (B, 4). Separate kernel (R15/R18).
// ---------------------------------------------------------------------------
__global__ __launch_bounds__(256) void local_agg_kernel(
    const int* __restrict__ inputs, const int* __restrict__ adj,
    const float* __restrict__ emb,
    const float* __restrict__ a0, const float* __restrict__ a1,
    const float* __restrict__ a2, const float* __restrict__ a3,
    float* __restrict__ hlocal_out)
{
  __shared__ float hs[L_][129];
  __shared__ float alds[4][129];
  __shared__ float att[13][51];
  const int b = blockIdx.x, tid = threadIdx.x;
  const int r0 = blockIdx.y * 13;
  const int nr = (L_ - r0) < 13 ? (L_ - r0) : 13;

  if (tid < 128){
    alds[0][tid] = a0[tid]; alds[1][tid] = a1[tid];
    alds[2][tid] = a2[tid]; alds[3][tid] = a3[tid];
  }
  for (int i = tid; i < L_*D_; i += 256){
    int r = i >> 7, d = i & 127;
    hs[r][d] = emb[(size_t)inputs[b*L_ + r]*D_ + d];
  }
  __syncthreads();

  for (int pth = tid; pth < nr*L_; pth += 256){
    int i = pth / L_, j = pth % L_;
    int at = adj[b*L_*L_ + (r0+i)*L_ + j];
    float lg = NEG_INF_;
    if (at >= 1 && at <= 4){
      const float* av = alds[at-1];
      float acc = 0.f;
      #pragma unroll 4
      for (int d = 0; d < D_; ++d) acc = fmaf(hs[r0+i][d]*hs[j][d], av[d], acc);
      lg = lrelu(acc);
    }
    att[i][j] = lg;
  }
  __syncthreads();

  if (tid < nr){
    float m = -1e30f;
    for (int j = 0; j < L_; ++j) m = fmaxf(m, att[tid][j]);
    float sum = 0.f;
    for (int j = 0; j < L_; ++j){ float e = fexp(att[tid][j]-m); att[tid][j] = e; sum += e; }
    float inv = frcp(sum);
    for (int j = 0; j < L_; ++j) att[tid][j] *= inv;
  }
  __syncthreads();

  for (int i2 = tid; i2 < nr*D_; i2 += 256){
    int r = i2 >> 7, d = i2 & 127;
    float acc = 0.f;
    #pragma unroll 5
    for (int j = 0; j < L_; ++j) acc = fmaf(att[r][j], hs[j][d], acc);
    hlocal_out[(size_t)b*L_*D_ + (size_t)(r0+r)*D_ + d] = acc;
  }
}

// ---------------------------------------------------------------------------
// Mega-prep (one launch): emb f32->f16 | gw3 frag pack | 2-level neighbor
// expansion | W' build (session-mean fused; reads raw f32 gw1).
// ---------------------------------------------------------------------------
__global__ __launch_bounds__(256) void prep_mega_kernel(
    const float* __restrict__ emb, _Float16* __restrict__ embh,
    const float* __restrict__ gw3, _Float16* __restrict__ gw3f,
    const float* __restrict__ gw1,
    const int* __restrict__ inputs, const int* __restrict__ adj_all,
    const float* __restrict__ num_w,
    int* __restrict__ n1, float* __restrict__ w0,
    int* __restrict__ n2, float* __restrict__ w1,
    const int* __restrict__ item, const int* __restrict__ mask,
    _Float16* __restrict__ wg)
{
  __shared__ float si[128];
  const int blk = blockIdx.x, tid = threadIdx.x;

  if (blk < 12500){
    int i = blk*256 + tid;
    float4 v = ((const float4*)emb)[i];
    union { _Float16 h[4]; uint2 u; } pk;
    pk.h[0] = (_Float16)v.x; pk.h[1] = (_Float16)v.y;
    pk.h[2] = (_Float16)v.z; pk.h[3] = (_Float16)v.w;
    ((uint2*)embh)[i] = pk.u;
  } else if (blk < 12532){
    int rel = blk - 12500;
    int hop = rel >> 4, bx = rel & 15;
    int idx = bx*256 + tid;
    int lane = idx & 63, n = (idx >> 6) & 7, kt = idx >> 9;
    int g4 = lane >> 4, col = lane & 15;
    const float* g3 = gw3 + (size_t)hop*256*128;
    size_t base = (size_t)hop*32768 + ((size_t)(kt*8 + n)*64 + lane)*8;
    #pragma unroll
    for (int j = 0; j < 8; ++j){
      int k = kt*32 + g4*8 + j;
      gw3f[base + j] = (_Float16)g3[(size_t)k*128 + n*16 + col];
    }
  } else if (blk < 16132){
    int t = (blk - 12532)*256 + tid;
    int i1 = t / S_;
    int s2 = t - i1*S_;
    int i0 = i1 / S_;
    int s1 = i1 - i0*S_;
    int parent0 = inputs[i0];
    int parent1 = adj_all[(size_t)parent0*S_ + s1];
    n2[t] = adj_all[(size_t)parent1*S_ + s2];
    w1[t] = num_w[(size_t)parent1*S_ + s2];
    if (s2 == 0){
      n1[i1] = parent1;
      w0[i1] = num_w[(size_t)parent0*S_ + s1];
    }
  } else {
    int g = blk - 16132;
    int hop = g >> 7, b = g & 127;
    if (tid < 128){
      float acc = 0.f, cnt = 0.f;
      for (int l = 0; l < L_; ++l){
        float mf = (float)mask[b*L_ + l];
        acc = fmaf(mf, emb[(size_t)item[b*L_+l]*D_ + tid], acc);
        cnt += mf;
      }
      si[tid] = acc / cnt;
    }
    __syncthreads();
    _Float16* wb = wg + ((size_t)(hop*128 + b)*32)*512;
    const float* g1 = gw1 + (size_t)hop*129*128;
    for (int i = 0; i < 8; ++i){
      int slot = i*256 + tid;
      int f = slot >> 6, l = slot & 63;
      int g4 = (l >> 4) & 3, col = l & 15;
      int t = f >> 3, n = f & 7;
      int k0 = t*32 + g4*8;
      union { _Float16 h[8]; uint4 q; } o;
      #pragma unroll
      for (int j = 0; j < 8; ++j)
        o.h[j] = (_Float16)(si[k0+j] * g1[(size_t)(k0+j)*128 + n*16 + col]);
      *(uint4*)(wb + (size_t)slot*8) = o.q;
    }
  }
}

// ---------------------------------------------------------------------------
// GlobalAggregator v16 = v15 with NP=16 pairs/wave (64/block).
// R19->R20 ladder showed block-amortization pays (-11us); one more halving:
// W' fill amortizes over 64 pairs, prefetch tail 1-in-16, barriers halve.
// Per-iteration live set unchanged; LOCKED at __launch_bounds__(256,2)
// (R4/R9/R17: anything tighter spills). LDS 79.2KB -> still 2 blocks/CU.
// Stage D: 4 sequential 16-row f16 MFMA batches over catl[64][264].
// ---------------------------------------------------------------------------
template<bool USE_IDS, bool OUTF32>
__global__ __launch_bounds__(256, 2) void gagg16_kernel(
    const _Float16* __restrict__ embh,
    const int* sv_ids0, const _Float16* sv_vals0,
    const int* nv_ids0, const _Float16* nv_vals0,
    const float* nw0, void* outp0, int M0, int nbpb0, int nblk0,
    const int* sv_ids1, const _Float16* sv_vals1,
    const int* nv_ids1, const _Float16* nv_vals1,
    const float* nw1, void* outp1, int M1, int nbpb1,
    const _Float16* __restrict__ wg,  const float* __restrict__ gw1_last,
    const float* __restrict__ gw2, const _Float16* __restrict__ gw3f,
    float* __restrict__ hout)
{
  __shared__ _Float16 wlds[32*512];           // 32768 B: W'_b frag image
  __shared__ _Float16 stash[4][12][132];      // 12672 B (wave-private)
  __shared__ _Float16 catl[64][264];          // 33792 B (block-shared)
  const int tid  = threadIdx.x;
  const int wid  = tid >> 6;
  const int lane = tid & 63;
  const int g4   = lane >> 4;
  const int col  = lane & 15;
  const bool colv = col < S_;
  const int sc_  = colv ? col : 0;

  const bool c1 = ((int)blockIdx.x >= nblk0);
  const int  blk = c1 ? (int)blockIdx.x - nblk0 : (int)blockIdx.x;
  const int*       sv_ids  = c1 ? sv_ids1  : sv_ids0;
  const _Float16*  sv_vals = c1 ? sv_vals1 : sv_vals0;
  const int*       nv_ids  = c1 ? nv_ids1  : nv_ids0;
  const _Float16*  nv_vals = c1 ? nv_vals1 : nv_vals0;
  const float*     nw      = c1 ? nw1      : nw0;
  void*            outp    = c1 ? outp1    : outp0;
  const int        M       = c1 ? M1       : M0;
  const int        nbpb    = c1 ? nbpb1    : nbpb0;

  const int b = blk / nbpb;
  const int j = blk - b*nbpb;

  // ---- cooperative W' load: 32768B = 2048 uint4, 8 per thread -----------
  {
    const uint4* src = (const uint4*)(wg + (size_t)b*32*512);
    uint4* dst = (uint4*)wlds;
    #pragma unroll
    for (int i = 0; i < 8; ++i)
      dst[i*256 + tid] = src[i*256 + tid];
  }
  __syncthreads();

  float g2v[8], glv[8];
  #pragma unroll
  for (int n = 0; n < 8; ++n){
    g2v[n] = gw2[n*16 + col];
    glv[n] = gw1_last[n*16 + col];
  }

  auto pidx = [&](int np_)->int{
    int li0 = j*64 + wid*16 + np_;
    int li  = li0 < M ? li0 : M-1;
    return b*M + li;
  };

  // ---- prefetch pipeline: ids 2 ahead, A-frag rows 1 ahead ---------------
  const half8 z8 = {0,0,0,0,0,0,0,0};
  half8 pf[4];
  int idn = 0;
  {
    const int p0_ = pidx(0);
    const _Float16* r0 = USE_IDS ? embh + (size_t)nv_ids[p0_*S_ + sc_]*D_
                                 : nv_vals + ((size_t)p0_*S_ + sc_)*D_;
    #pragma unroll
    for (int t = 0; t < 4; ++t)
      pf[t] = colv ? *(const half8*)(r0 + t*32 + g4*8) : z8;
    if (USE_IDS) idn = nv_ids[pidx(1)*S_ + sc_];
  }

  for (int np = 0; np < 16; ++np){
    const int p = pidx(np);

    // current pair's frags (loads had a full iteration to land)
    half8 af[4];
    #pragma unroll
    for (int t = 0; t < 4; ++t) af[t] = colv ? pf[t] : z8;

    // issue NEXT pair's row loads + id 2 ahead
    if (np < 15){
      const _Float16* rn = USE_IDS ? embh + (size_t)idn*D_
                                   : nv_vals + ((size_t)pidx(np+1)*S_ + sc_)*D_;
      #pragma unroll
      for (int t = 0; t < 4; ++t)
        pf[t] = colv ? *(const half8*)(rn + t*32 + g4*8) : z8;
      if (USE_IDS && np < 14) idn = nv_ids[pidx(np+2)*S_ + sc_];
    }

    // hoist independent loads: nw + sv row
    float nwv[4];
    #pragma unroll
    for (int r = 0; r < 4; ++r){
      int s = g4*4 + r;
      nwv[r] = nw[p*S_ + (s < S_ ? s : 0)];
    }
    const _Float16* svrow = USE_IDS ? embh + (size_t)sv_ids[p]*D_
                                    : sv_vals + (size_t)p*D_;
    unsigned sv2q = *(const unsigned*)(svrow + 2*lane);

    // stash writes + MFMA
    #pragma unroll
    for (int t = 0; t < 4; ++t){
      if (colv){
        union { half8 v; uint2 q[2]; } ua;
        ua.v = af[t];
        _Float16* sp = &stash[wid][col][t*32 + g4*8];
        *(uint2*)sp       = ua.q[0];
        *(uint2*)(sp + 4) = ua.q[1];
      }
    }
    f32x4 acc[8];
    #pragma unroll
    for (int n = 0; n < 8; ++n) acc[n] = (f32x4){0.f,0.f,0.f,0.f};
    #pragma unroll
    for (int t = 0; t < 4; ++t){
      #pragma unroll
      for (int n = 0; n < 8; ++n){
        half8 wf = *(const half8*)(wlds + ((size_t)(t*8+n)*64 + lane)*8);
        acc[n] = __builtin_amdgcn_mfma_f32_16x16x32_f16(af[t], wf, acc[n], 0, 0, 0);
      }
    }

    // -------- nw rank-1 (VALU) + scores -> softmax -> stage C -> catl -----
    float sc4[4];
    #pragma unroll
    for (int r = 0; r < 4; ++r){
      float pr = 0.f;
      #pragma unroll
      for (int n = 0; n < 8; ++n){
        float tv = acc[n][r] + nwv[r]*glv[n];
        pr = fmaf(lrelu(tv), g2v[n], pr);
      }
      pr += __shfl_xor(pr, 1); pr += __shfl_xor(pr, 2);
      pr += __shfl_xor(pr, 4); pr += __shfl_xor(pr, 8);
      sc4[r] = pr;
    }
    float w[S_];
    {
      float ss[S_];
      #pragma unroll
      for (int grp = 0; grp < 3; ++grp)
        #pragma unroll
        for (int r = 0; r < 4; ++r)
          ss[grp*4 + r] = __shfl(sc4[r], grp*16);
      float m01 = fmaxf(ss[0], ss[1]),  m23 = fmaxf(ss[2], ss[3]);
      float m45 = fmaxf(ss[4], ss[5]),  m67 = fmaxf(ss[6], ss[7]);
      float m89 = fmaxf(ss[8], ss[9]),  mab = fmaxf(ss[10], ss[11]);
      float m = fmaxf(fmaxf(fmaxf(m01, m23), fmaxf(m45, m67)), fmaxf(m89, mab));
      float sum = 0.f;
      #pragma unroll
      for (int s = 0; s < S_; ++s){ ss[s] = fexp(ss[s]-m); sum += ss[s]; }
      float inv = frcp(sum);
      #pragma unroll
      for (int s = 0; s < S_; ++s) w[s] = ss[s]*inv;
    }
    float aggx = 0.f, aggy = 0.f;
    #pragma unroll
    for (int s = 0; s < S_; ++s){
      union { unsigned q; _Float16 h[2]; } v;
      v.q = *(const unsigned*)&stash[wid][s][2*lane];
      aggx = fmaf(w[s], (float)v.h[0], aggx);
      aggy = fmaf(w[s], (float)v.h[1], aggy);
    }
    const int row = wid*16 + np;
    *(unsigned*)&catl[row][2*lane] = sv2q;
    union { unsigned q; _Float16 h[2]; } pk;
    pk.h[0] = (_Float16)aggx; pk.h[1] = (_Float16)aggy;
    *(unsigned*)&catl[row][D_ + 2*lane] = pk.q;
  }

  __syncthreads();   // catl is block-shared

  // -------- stage D: 4 x [16x256]@[256x128] f16 MFMA batches --------------
  const half8* g3fp = (const half8*)gw3f;
  #pragma unroll
  for (int hb = 0; hb < 4; ++hb){
    f32x4 dacc[2];
    dacc[0] = (f32x4){0.f,0.f,0.f,0.f};
    dacc[1] = (f32x4){0.f,0.f,0.f,0.f};

    #pragma unroll
    for (int kt = 0; kt < 8; ++kt){
      half8 afr = *(const half8*)&catl[hb*16 + col][kt*32 + g4*8];
      #pragma unroll
      for (int nn = 0; nn < 2; ++nn){
        int n = wid*2 + nn;
        dacc[nn] = __builtin_amdgcn_mfma_f32_16x16x32_f16(afr, g3fp[(kt*8+n)*64 + lane], dacc[nn], 0, 0, 0);
      }
    }

    #pragma unroll
    for (int nn = 0; nn < 2; ++nn){
      int n = wid*2 + nn;
      #pragma unroll
      for (int r = 0; r < 4; ++r){
        int li = j*64 + hb*16 + g4*4 + r;
        if (li < M){
          size_t off = (size_t)(b*M + li)*D_ + n*16 + col;
          float v = fmaxf(dacc[nn][r], 0.f);
          if (OUTF32){
            ((float*)outp)[off] = v;          // s_global region
            hout[off] += v;                   // output = h_local + s_global
          } else {
            ((_Float16*)outp)[off] = (_Float16)v;
          }
        }
      }
    }
  }
}

extern "C" void kernel_launch(void* const* d_in, const int* in_sizes, int n_in,
                              void* d_out, int out_size, void* d_ws, size_t ws_size,
                              hipStream_t stream)
{
  const int*   inputs  = (const int*)  d_in[0];
  const int*   adj     = (const int*)  d_in[1];
  const int*   mask    = (const int*)  d_in[2];
  const int*   item    = (const int*)  d_in[3];
  const float* emb     = (const float*)d_in[4];
  const int*   adj_all = (const int*)  d_in[5];
  const float* num_w   = (const float*)d_in[6];
  const float* a0      = (const float*)d_in[7];
  const float* a1      = (const float*)d_in[8];
  const float* a2      = (const float*)d_in[9];
  const float* a3      = (const float*)d_in[10];
  const float* gw1     = (const float*)d_in[11];  // [2][129][128]
  const float* gw2     = (const float*)d_in[12];  // [2][128]
  const float* gw3     = (const float*)d_in[13];  // [2][256][128]

  float* out     = (float*)d_out;
  float* hlocal  = out;
  float* sglobal = out + B_*L_*D_;

  char* ws = (char*)d_ws;
  size_t off = 0;
  auto alloc = [&](size_t bytes)->char*{
    char* pp = ws + off; off += (bytes + 255) & ~(size_t)255; return pp;
  };
  int*      n1     = (int*)  alloc((size_t)B_*L_*S_*sizeof(int));
  float*    w0     = (float*)alloc((size_t)B_*L_*S_*sizeof(float));
  int*      n2     = (int*)  alloc((size_t)B_*L_*S_*S_*sizeof(int));
  float*    w1     = (float*)alloc((size_t)B_*L_*S_*S_*sizeof(float));
  _Float16* out0h  = (_Float16*)alloc((size_t)B_*L_*D_*sizeof(_Float16));
  _Float16* out1h  = (_Float16*)alloc((size_t)B_*L_*S_*D_*sizeof(_Float16));
  _Float16* embh   = (_Float16*)alloc((size_t)100000*D_*sizeof(_Float16));
  _Float16* gw3f   = (_Float16*)alloc((size_t)2*32768*sizeof(_Float16));
  _Float16* wgAll  = (_Float16*)alloc((size_t)2*128*32*512*sizeof(_Float16)); // 8.4MB

  // 1) mega-prep: emb->f16 | gw3 frags | 2-hop nbr expansion | W' build
  prep_mega_kernel<<<16388, 256, 0, stream>>>(
      emb, embh, gw3, gw3f, gw1,
      inputs, adj_all, num_w, n1, w0, n2, w1,
      item, mask, wgAll);

  // 2) local GAT (separate small kernel)
  local_agg_kernel<<<dim3(B_,4), 256, 0, stream>>>(inputs, adj, emb, a0, a1, a2, a3, hlocal);

  // 3) fused hop0 (pass A + pass B), 64 pairs/block
  {
    const int nbpbA = 1;                 // ceil(50/64)
    const int nbpbB = 10;                // ceil(600/64)
    const int nblkA = B_*nbpbA;          // 128
    const int nblkB = B_*nbpbB;          // 1280
    gagg16_kernel<true,false><<<nblkA + nblkB, 256, 0, stream>>>(
        embh,
        inputs, nullptr, n1, nullptr, w0, out0h, L_,   nbpbA, nblkA,
        n1,     nullptr, n2, nullptr, w1, out1h, L_*S_, nbpbB,
        wgAll, gw1 + 128*128, gw2, gw3f, nullptr);
  }
  // 4) hop1 (pass C): writes sglobal and folds out = h_local + s_global
  {
    const int nbpbC = 1;
    const int nblkC = B_*nbpbC;          // 128
    gagg16_kernel<false,true><<<nblkC, 256, 0, stream>>>(
        embh,
        nullptr, out0h, nullptr, out1h, w0, sglobal, L_, nbpbC, nblkC,
        nullptr, out0h, nullptr, out1h, w0, sglobal, L_, nbpbC,
        wgAll + (size_t)128*32*512, gw1 + 129*128 + 128*128, gw2 + 128, gw3f + 32768,
        hlocal);
  }
}

// Round 22
// 182.441 us; speedup vs baseline: 1.0784x; 1.0784x over previous
//
#include <hip/hip_runtime.h>
#include <hip/hip_bf16.h>
#include <math.h>

#define B_ 128
#define L_ 50
#define D_ 128
#define S_ 12
#define NEG_INF_ -9e15f

typedef __attribute__((ext_vector_type(8))) _Float16 half8;
typedef __attribute__((ext_vector_type(4))) float f32x4;

static __device__ __forceinline__ float lrelu(float x){ return fmaxf(x, 0.2f*x); }
static __device__ __forceinline__ float fexp(float x){ return __expf(x); }
static __device__ __forceinline__ float frcp(float x){ return __builtin_amdgcn_rcpf(x); }

// ---------------------------------------------------------------------------
// Local aggregator: 4-edge-type GAT. Grid (B, 4). Separate kernel (R15/R18).
// ---------------------------------------------------------------------------
__global__ __launch_bounds__(256) void local_agg_kernel(
    const int* __restrict__ inputs, const int* __restrict__ adj,
    const float* __restrict__ emb,
    const float* __restrict__ a0, const float* __restrict__ a1,
    const float* __restrict__ a2, const float* __restrict__ a3,
    float* __restrict__ hlocal_out)
{
  __shared__ float hs[L_][129];
  __shared__ float alds[4][129];
  __shared__ float att[13][51];
  const int b = blockIdx.x, tid = threadIdx.x;
  const int r0 = blockIdx.y * 13;
  const int nr = (L_ - r0) < 13 ? (L_ - r0) : 13;

  if (tid < 128){
    alds[0][tid] = a0[tid]; alds[1][tid] = a1[tid];
    alds[2][tid] = a2[tid]; alds[3][tid] = a3[tid];
  }
  for (int i = tid; i < L_*D_; i += 256){
    int r = i >> 7, d = i & 127;
    hs[r][d] = emb[(size_t)inputs[b*L_ + r]*D_ + d];
  }
  __syncthreads();

  for (int pth = tid; pth < nr*L_; pth += 256){
    int i = pth / L_, j = pth % L_;
    int at = adj[b*L_*L_ + (r0+i)*L_ + j];
    float lg = NEG_INF_;
    if (at >= 1 && at <= 4){
      const float* av = alds[at-1];
      float acc = 0.f;
      #pragma unroll 4
      for (int d = 0; d < D_; ++d) acc = fmaf(hs[r0+i][d]*hs[j][d], av[d], acc);
      lg = lrelu(acc);
    }
    att[i][j] = lg;
  }
  __syncthreads();

  if (tid < nr){
    float m = -1e30f;
    for (int j = 0; j < L_; ++j) m = fmaxf(m, att[tid][j]);
    float sum = 0.f;
    for (int j = 0; j < L_; ++j){ float e = fexp(att[tid][j]-m); att[tid][j] = e; sum += e; }
    float inv = frcp(sum);
    for (int j = 0; j < L_; ++j) att[tid][j] *= inv;
  }
  __syncthreads();

  for (int i2 = tid; i2 < nr*D_; i2 += 256){
    int r = i2 >> 7, d = i2 & 127;
    float acc = 0.f;
    #pragma unroll 5
    for (int j = 0; j < L_; ++j) acc = fmaf(att[r][j], hs[j][d], acc);
    hlocal_out[(size_t)b*L_*D_ + (size_t)(r0+r)*D_ + d] = acc;
  }
}

// ---------------------------------------------------------------------------
// Mega-prep (one launch): emb f32->f16 | gw3 frag pack | 2-level neighbor
// expansion | W' build (session-mean fused; reads raw f32 gw1).
// ---------------------------------------------------------------------------
__global__ __launch_bounds__(256) void prep_mega_kernel(
    const float* __restrict__ emb, _Float16* __restrict__ embh,
    const float* __restrict__ gw3, _Float16* __restrict__ gw3f,
    const float* __restrict__ gw1,
    const int* __restrict__ inputs, const int* __restrict__ adj_all,
    const float* __restrict__ num_w,
    int* __restrict__ n1, float* __restrict__ w0,
    int* __restrict__ n2, float* __restrict__ w1,
    const int* __restrict__ item, const int* __restrict__ mask,
    _Float16* __restrict__ wg)
{
  __shared__ float si[128];
  const int blk = blockIdx.x, tid = threadIdx.x;

  if (blk < 12500){
    int i = blk*256 + tid;
    float4 v = ((const float4*)emb)[i];
    union { _Float16 h[4]; uint2 u; } pk;
    pk.h[0] = (_Float16)v.x; pk.h[1] = (_Float16)v.y;
    pk.h[2] = (_Float16)v.z; pk.h[3] = (_Float16)v.w;
    ((uint2*)embh)[i] = pk.u;
  } else if (blk < 12532){
    int rel = blk - 12500;
    int hop = rel >> 4, bx = rel & 15;
    int idx = bx*256 + tid;
    int lane = idx & 63, n = (idx >> 6) & 7, kt = idx >> 9;
    int g4 = lane >> 4, col = lane & 15;
    const float* g3 = gw3 + (size_t)hop*256*128;
    size_t base = (size_t)hop*32768 + ((size_t)(kt*8 + n)*64 + lane)*8;
    #pragma unroll
    for (int j = 0; j < 8; ++j){
      int k = kt*32 + g4*8 + j;
      gw3f[base + j] = (_Float16)g3[(size_t)k*128 + n*16 + col];
    }
  } else if (blk < 16132){
    int t = (blk - 12532)*256 + tid;
    int i1 = t / S_;
    int s2 = t - i1*S_;
    int i0 = i1 / S_;
    int s1 = i1 - i0*S_;
    int parent0 = inputs[i0];
    int parent1 = adj_all[(size_t)parent0*S_ + s1];
    n2[t] = adj_all[(size_t)parent1*S_ + s2];
    w1[t] = num_w[(size_t)parent1*S_ + s2];
    if (s2 == 0){
      n1[i1] = parent1;
      w0[i1] = num_w[(size_t)parent0*S_ + s1];
    }
  } else {
    int g = blk - 16132;
    int hop = g >> 7, b = g & 127;
    if (tid < 128){
      float acc = 0.f, cnt = 0.f;
      for (int l = 0; l < L_; ++l){
        float mf = (float)mask[b*L_ + l];
        acc = fmaf(mf, emb[(size_t)item[b*L_+l]*D_ + tid], acc);
        cnt += mf;
      }
      si[tid] = acc / cnt;
    }
    __syncthreads();
    _Float16* wb = wg + ((size_t)(hop*128 + b)*32)*512;
    const float* g1 = gw1 + (size_t)hop*129*128;
    for (int i = 0; i < 8; ++i){
      int slot = i*256 + tid;
      int f = slot >> 6, l = slot & 63;
      int g4 = (l >> 4) & 3, col = l & 15;
      int t = f >> 3, n = f & 7;
      int k0 = t*32 + g4*8;
      union { _Float16 h[8]; uint4 q; } o;
      #pragma unroll
      for (int j = 0; j < 8; ++j)
        o.h[j] = (_Float16)(si[k0+j] * g1[(size_t)(k0+j)*128 + n*16 + col]);
      *(uint4*)(wb + (size_t)slot*8) = o.q;
    }
  }
}

// ---------------------------------------------------------------------------
// GlobalAggregator v15 (R20 optimum): NP=8 pairs/wave (32/block).
// W' cooperative 32KB load amortizes over 32 pairs; prefetch tail 1-in-8.
// LOCKED at __launch_bounds__(256,2) (R4/R9/R17: anything tighter spills).
// NP=16 (R21) was flat on this kernel and regressed the small passes ->
// NP=8 is the measured optimum. Stage D: 2 x 16-row f16 MFMA batches.
// ---------------------------------------------------------------------------
template<bool USE_IDS, bool OUTF32>
__global__ __launch_bounds__(256, 2) void gagg15_kernel(
    const _Float16* __restrict__ embh,
    const int* sv_ids0, const _Float16* sv_vals0,
    const int* nv_ids0, const _Float16* nv_vals0,
    const float* nw0, void* outp0, int M0, int nbpb0, int nblk0,
    const int* sv_ids1, const _Float16* sv_vals1,
    const int* nv_ids1, const _Float16* nv_vals1,
    const float* nw1, void* outp1, int M1, int nbpb1,
    const _Float16* __restrict__ wg,  const float* __restrict__ gw1_last,
    const float* __restrict__ gw2, const _Float16* __restrict__ gw3f,
    float* __restrict__ hout)
{
  __shared__ _Float16 wlds[32*512];           // 32768 B: W'_b frag image
  __shared__ _Float16 stash[4][12][132];      // 12672 B (wave-private)
  __shared__ _Float16 catl[32][264];          // 16896 B (block-shared)
  const int tid  = threadIdx.x;
  const int wid  = tid >> 6;
  const int lane = tid & 63;
  const int g4   = lane >> 4;
  const int col  = lane & 15;
  const bool colv = col < S_;
  const int sc_  = colv ? col : 0;

  const bool c1 = ((int)blockIdx.x >= nblk0);
  const int  blk = c1 ? (int)blockIdx.x - nblk0 : (int)blockIdx.x;
  const int*       sv_ids  = c1 ? sv_ids1  : sv_ids0;
  const _Float16*  sv_vals = c1 ? sv_vals1 : sv_vals0;
  const int*       nv_ids  = c1 ? nv_ids1  : nv_ids0;
  const _Float16*  nv_vals = c1 ? nv_vals1 : nv_vals0;
  const float*     nw      = c1 ? nw1      : nw0;
  void*            outp    = c1 ? outp1    : outp0;
  const int        M       = c1 ? M1       : M0;
  const int        nbpb    = c1 ? nbpb1    : nbpb0;

  const int b = blk / nbpb;
  const int j = blk - b*nbpb;

  // ---- cooperative W' load: 32768B = 2048 uint4, 8 per thread -----------
  {
    const uint4* src = (const uint4*)(wg + (size_t)b*32*512);
    uint4* dst = (uint4*)wlds;
    #pragma unroll
    for (int i = 0; i < 8; ++i)
      dst[i*256 + tid] = src[i*256 + tid];
  }
  __syncthreads();

  float g2v[8], glv[8];
  #pragma unroll
  for (int n = 0; n < 8; ++n){
    g2v[n] = gw2[n*16 + col];
    glv[n] = gw1_last[n*16 + col];
  }

  auto pidx = [&](int np_)->int{
    int li0 = j*32 + wid*8 + np_;
    int li  = li0 < M ? li0 : M-1;
    return b*M + li;
  };

  // ---- prefetch pipeline: ids 2 ahead, A-frag rows 1 ahead ---------------
  const half8 z8 = {0,0,0,0,0,0,0,0};
  half8 pf[4];
  int idn = 0;
  {
    const int p0_ = pidx(0);
    const _Float16* r0 = USE_IDS ? embh + (size_t)nv_ids[p0_*S_ + sc_]*D_
                                 : nv_vals + ((size_t)p0_*S_ + sc_)*D_;
    #pragma unroll
    for (int t = 0; t < 4; ++t)
      pf[t] = colv ? *(const half8*)(r0 + t*32 + g4*8) : z8;
    if (USE_IDS) idn = nv_ids[pidx(1)*S_ + sc_];
  }

  for (int np = 0; np < 8; ++np){
    const int p = pidx(np);

    // current pair's frags (loads had a full iteration to land)
    half8 af[4];
    #pragma unroll
    for (int t = 0; t < 4; ++t) af[t] = colv ? pf[t] : z8;

    // issue NEXT pair's row loads + id 2 ahead
    if (np < 7){
      const _Float16* rn = USE_IDS ? embh + (size_t)idn*D_
                                   : nv_vals + ((size_t)pidx(np+1)*S_ + sc_)*D_;
      #pragma unroll
      for (int t = 0; t < 4; ++t)
        pf[t] = colv ? *(const half8*)(rn + t*32 + g4*8) : z8;
      if (USE_IDS && np < 6) idn = nv_ids[pidx(np+2)*S_ + sc_];
    }

    // hoist independent loads: nw + sv row
    float nwv[4];
    #pragma unroll
    for (int r = 0; r < 4; ++r){
      int s = g4*4 + r;
      nwv[r] = nw[p*S_ + (s < S_ ? s : 0)];
    }
    const _Float16* svrow = USE_IDS ? embh + (size_t)sv_ids[p]*D_
                                    : sv_vals + (size_t)p*D_;
    unsigned sv2q = *(const unsigned*)(svrow + 2*lane);

    // stash writes + MFMA
    #pragma unroll
    for (int t = 0; t < 4; ++t){
      if (colv){
        union { half8 v; uint2 q[2]; } ua;
        ua.v = af[t];
        _Float16* sp = &stash[wid][col][t*32 + g4*8];
        *(uint2*)sp       = ua.q[0];
        *(uint2*)(sp + 4) = ua.q[1];
      }
    }
    f32x4 acc[8];
    #pragma unroll
    for (int n = 0; n < 8; ++n) acc[n] = (f32x4){0.f,0.f,0.f,0.f};
    #pragma unroll
    for (int t = 0; t < 4; ++t){
      #pragma unroll
      for (int n = 0; n < 8; ++n){
        half8 wf = *(const half8*)(wlds + ((size_t)(t*8+n)*64 + lane)*8);
        acc[n] = __builtin_amdgcn_mfma_f32_16x16x32_f16(af[t], wf, acc[n], 0, 0, 0);
      }
    }

    // -------- nw rank-1 (VALU) + scores -> softmax -> stage C -> catl -----
    float sc4[4];
    #pragma unroll
    for (int r = 0; r < 4; ++r){
      float pr = 0.f;
      #pragma unroll
      for (int n = 0; n < 8; ++n){
        float tv = acc[n][r] + nwv[r]*glv[n];
        pr = fmaf(lrelu(tv), g2v[n], pr);
      }
      pr += __shfl_xor(pr, 1); pr += __shfl_xor(pr, 2);
      pr += __shfl_xor(pr, 4); pr += __shfl_xor(pr, 8);
      sc4[r] = pr;
    }
    float w[S_];
    {
      float ss[S_];
      #pragma unroll
      for (int grp = 0; grp < 3; ++grp)
        #pragma unroll
        for (int r = 0; r < 4; ++r)
          ss[grp*4 + r] = __shfl(sc4[r], grp*16);
      float m01 = fmaxf(ss[0], ss[1]),  m23 = fmaxf(ss[2], ss[3]);
      float m45 = fmaxf(ss[4], ss[5]),  m67 = fmaxf(ss[6], ss[7]);
      float m89 = fmaxf(ss[8], ss[9]),  mab = fmaxf(ss[10], ss[11]);
      float m = fmaxf(fmaxf(fmaxf(m01, m23), fmaxf(m45, m67)), fmaxf(m89, mab));
      float sum = 0.f;
      #pragma unroll
      for (int s = 0; s < S_; ++s){ ss[s] = fexp(ss[s]-m); sum += ss[s]; }
      float inv = frcp(sum);
      #pragma unroll
      for (int s = 0; s < S_; ++s) w[s] = ss[s]*inv;
    }
    float aggx = 0.f, aggy = 0.f;
    #pragma unroll
    for (int s = 0; s < S_; ++s){
      union { unsigned q; _Float16 h[2]; } v;
      v.q = *(const unsigned*)&stash[wid][s][2*lane];
      aggx = fmaf(w[s], (float)v.h[0], aggx);
      aggy = fmaf(w[s], (float)v.h[1], aggy);
    }
    const int row = wid*8 + np;
    *(unsigned*)&catl[row][2*lane] = sv2q;
    union { unsigned q; _Float16 h[2]; } pk;
    pk.h[0] = (_Float16)aggx; pk.h[1] = (_Float16)aggy;
    *(unsigned*)&catl[row][D_ + 2*lane] = pk.q;
  }

  __syncthreads();   // catl is block-shared

  // -------- stage D: 2 x [16x256]@[256x128] f16 MFMA batches --------------
  const half8* g3fp = (const half8*)gw3f;
  #pragma unroll
  for (int hb = 0; hb < 2; ++hb){
    f32x4 dacc[2];
    dacc[0] = (f32x4){0.f,0.f,0.f,0.f};
    dacc[1] = (f32x4){0.f,0.f,0.f,0.f};

    #pragma unroll
    for (int kt = 0; kt < 8; ++kt){
      half8 afr = *(const half8*)&catl[hb*16 + col][kt*32 + g4*8];
      #pragma unroll
      for (int nn = 0; nn < 2; ++nn){
        int n = wid*2 + nn;
        dacc[nn] = __builtin_amdgcn_mfma_f32_16x16x32_f16(afr, g3fp[(kt*8+n)*64 + lane], dacc[nn], 0, 0, 0);
      }
    }

    #pragma unroll
    for (int nn = 0; nn < 2; ++nn){
      int n = wid*2 + nn;
      #pragma unroll
      for (int r = 0; r < 4; ++r){
        int li = j*32 + hb*16 + g4*4 + r;
        if (li < M){
          size_t off = (size_t)(b*M + li)*D_ + n*16 + col;
          float v = fmaxf(dacc[nn][r], 0.f);
          if (OUTF32){
            ((float*)outp)[off] = v;          // s_global region
            hout[off] += v;                   // output = h_local + s_global
          } else {
            ((_Float16*)outp)[off] = (_Float16)v;
          }
        }
      }
    }
  }
}

extern "C" void kernel_launch(void* const* d_in, const int* in_sizes, int n_in,
                              void* d_out, int out_size, void* d_ws, size_t ws_size,
                              hipStream_t stream)
{
  const int*   inputs  = (const int*)  d_in[0];
  const int*   adj     = (const int*)  d_in[1];
  const int*   mask    = (const int*)  d_in[2];
  const int*   item    = (const int*)  d_in[3];
  const float* emb     = (const float*)d_in[4];
  const int*   adj_all = (const int*)  d_in[5];
  const float* num_w   = (const float*)d_in[6];
  const float* a0      = (const float*)d_in[7];
  const float* a1      = (const float*)d_in[8];
  const float* a2      = (const float*)d_in[9];
  const float* a3      = (const float*)d_in[10];
  const float* gw1     = (const float*)d_in[11];  // [2][129][128]
  const float* gw2     = (const float*)d_in[12];  // [2][128]
  const float* gw3     = (const float*)d_in[13];  // [2][256][128]

  float* out     = (float*)d_out;
  float* hlocal  = out;
  float* sglobal = out + B_*L_*D_;

  char* ws = (char*)d_ws;
  size_t off = 0;
  auto alloc = [&](size_t bytes)->char*{
    char* pp = ws + off; off += (bytes + 255) & ~(size_t)255; return pp;
  };
  int*      n1     = (int*)  alloc((size_t)B_*L_*S_*sizeof(int));
  float*    w0     = (float*)alloc((size_t)B_*L_*S_*sizeof(float));
  int*      n2     = (int*)  alloc((size_t)B_*L_*S_*S_*sizeof(int));
  float*    w1     = (float*)alloc((size_t)B_*L_*S_*S_*sizeof(float));
  _Float16* out0h  = (_Float16*)alloc((size_t)B_*L_*D_*sizeof(_Float16));
  _Float16* out1h  = (_Float16*)alloc((size_t)B_*L_*S_*D_*sizeof(_Float16));
  _Float16* embh   = (_Float16*)alloc((size_t)100000*D_*sizeof(_Float16));
  _Float16* gw3f   = (_Float16*)alloc((size_t)2*32768*sizeof(_Float16));
  _Float16* wgAll  = (_Float16*)alloc((size_t)2*128*32*512*sizeof(_Float16)); // 8.4MB

  // 1) mega-prep: emb->f16 | gw3 frags | 2-hop nbr expansion | W' build
  prep_mega_kernel<<<16388, 256, 0, stream>>>(
      emb, embh, gw3, gw3f, gw1,
      inputs, adj_all, num_w, n1, w0, n2, w1,
      item, mask, wgAll);

  // 2) local GAT (separate small kernel)
  local_agg_kernel<<<dim3(B_,4), 256, 0, stream>>>(inputs, adj, emb, a0, a1, a2, a3, hlocal);

  // 3) fused hop0 (pass A + pass B), 32 pairs/block
  {
    const int nbpbA = 2;                 // ceil(50/32)
    const int nbpbB = 19;                // ceil(600/32)
    const int nblkA = B_*nbpbA;          // 256
    const int nblkB = B_*nbpbB;          // 2432
    gagg15_kernel<true,false><<<nblkA + nblkB, 256, 0, stream>>>(
        embh,
        inputs, nullptr, n1, nullptr, w0, out0h, L_,   nbpbA, nblkA,
        n1,     nullptr, n2, nullptr, w1, out1h, L_*S_, nbpbB,
        wgAll, gw1 + 128*128, gw2, gw3f, nullptr);
  }
  // 4) hop1 (pass C): writes sglobal and folds out = h_local + s_global
  {
    const int nbpbC = 2;
    const int nblkC = B_*nbpbC;          // 256
    gagg15_kernel<false,true><<<nblkC, 256, 0, stream>>>(
        embh,
        nullptr, out0h, nullptr, out1h, w0, sglobal, L_, nbpbC, nblkC,
        nullptr, out0h, nullptr, out1h, w0, sglobal, L_, nbpbC,
        wgAll + (size_t)128*32*512, gw1 + 129*128 + 128*128, gw2 + 128, gw3f + 32768,
        hlocal);
  }
}